// Round 7
// baseline (148.605 us; speedup 1.0000x reference)
//
#include <hip/hip_runtime.h>
#include <math.h>

#define B 16
#define N 32
#define M 64
#define D 512
#define NM (N * M)          // 2048
#define NBQ (B * NM)        // 32768
#define NUM_NEGS 32
#define SMOOTHING 0.1f
#define TD0 (1.0f - SMOOTHING)                    // 0.9
#define TDN (SMOOTHING / (float)(NUM_NEGS - 1))   // 0.1/31
#define TDSUM (TD0 + (float)NUM_NEGS * TDN)

// ---------- bf16 helpers (manual, RNE) ----------
__device__ __forceinline__ unsigned int f2bf(float f) {
    unsigned int u = __float_as_uint(f);
    return (u + 0x7FFFu + ((u >> 16) & 1u)) >> 16;
}
__device__ __forceinline__ float dot8_bf16(uint4 w, float4 s0, float4 s1) {
    float e0 = __uint_as_float(w.x << 16);
    float e1 = __uint_as_float(w.x & 0xFFFF0000u);
    float e2 = __uint_as_float(w.y << 16);
    float e3 = __uint_as_float(w.y & 0xFFFF0000u);
    float e4 = __uint_as_float(w.z << 16);
    float e5 = __uint_as_float(w.z & 0xFFFF0000u);
    float e6 = __uint_as_float(w.w << 16);
    float e7 = __uint_as_float(w.w & 0xFFFF0000u);
    return e0 * s0.x + e1 * s0.y + e2 * s0.z + e3 * s0.w
         + e4 * s1.x + e5 * s1.y + e6 * s1.z + e7 * s1.w;
}

// Streaming c -> bf16 (16,777,216 floats, 8 per thread, 8192 x 256 exact).
__global__ __launch_bounds__(256) void convert_c_kernel(
    const float* __restrict__ c, uint4* __restrict__ cb)
{
    const size_t i = (size_t)blockIdx.x * 256 + threadIdx.x;
    const float4* cp = reinterpret_cast<const float4*>(c);
    const float4 a = cp[2 * i];
    const float4 b4 = cp[2 * i + 1];
    uint4 w;
    w.x = f2bf(a.x)  | (f2bf(a.y)  << 16);
    w.y = f2bf(a.z)  | (f2bf(a.w)  << 16);
    w.z = f2bf(b4.x) | (f2bf(b4.y) << 16);
    w.w = f2bf(b4.z) | (f2bf(b4.w) << 16);
    cb[i] = w;
}

// ---------- main kernel: one WAVE per q, no LDS, no barriers ----------
__global__ __launch_bounds__(256) void ce_main_bf16_kernel(
    const float* __restrict__ s,              // (B, NM, D) fp32
    const uint4* __restrict__ cb,             // (B*NM, D/8) bf16-packed rows
    const int* __restrict__ pad,
    const int* __restrict__ valid,
    const int* __restrict__ inds,
    float4* __restrict__ partials)
{
    // 8192 blocks; XCD-batch affinity: XCD x owns batches {x, x+8}.
    const int p    = blockIdx.x;
    const int x    = p & 7;
    const int i    = p >> 3;                  // 0..1023
    const int b    = x + ((i >> 9) << 3);     // batch
    const int wave = threadIdx.x >> 6;
    const int lane = threadIdx.x & 63;
    const int q    = (i & 511) * 4 + wave;    // this wave's q
    const int bq   = b * NM + q;

    // Per-lane setup: lane k (1..32) owns neg k-1. Raw loads; converted only
    // in the epilogue so their latency hides under the entire dot phase.
    int col_r = bq, row_r = bq;
    int vraw = 1;
    if (lane >= 1 && lane <= NUM_NEGS) {
        const size_t si = ((size_t)bq * NUM_NEGS + (lane - 1)) * 3;
        const int bb = inds[si + 0];
        const int rr = inds[si + 1];
        const int cc = inds[si + 2];
        col_r = bb * NM + cc;
        row_r = bb * NM + rr;
        vraw  = valid[((size_t)bb * NM + rr) * NM + cc];
    }
    const int padraw = pad[(size_t)bq * M];   // wave-uniform broadcast load

    // s-row in registers: lane owns elements 8*lane .. 8*lane+7.
    const float4* sp = reinterpret_cast<const float4*>(s + (size_t)bq * D);
    const float4 s0 = sp[2 * lane];
    const float4 s1 = sp[2 * lane + 1];

    // 33 dots, fully in-wave; lane j keeps dot j after a full butterfly.
    float dotreg = 0.0f;
    #pragma unroll
    for (int j = 0; j <= NUM_NEGS; ++j) {
        const int col = __shfl(col_r, j, 64);
        const int row = __shfl(row_r, j, 64);
        const uint4 w = cb[(size_t)col * (D / 8) + lane];
        float4 t0 = s0, t1 = s1;
        if (row != bq) {   // wave-uniform; never taken for these inputs
            const float4* spx = reinterpret_cast<const float4*>(s + (size_t)row * D);
            t0 = spx[2 * lane];
            t1 = spx[2 * lane + 1];
        }
        float sum = dot8_bf16(w, t0, t1);
        #pragma unroll
        for (int off = 32; off; off >>= 1) sum += __shfl_xor(sum, off, 64);
        if (lane == j) dotreg = sum;
    }

    // In-wave epilogue (no barrier): lane k holds dots[k], k<=32.
    float dj = (lane <= NUM_NEGS) ? dotreg : -INFINITY;
    if (lane >= 1 && lane <= NUM_NEGS && !vraw) dj = 0.0f;
    float mx = dj;
    #pragma unroll
    for (int off = 32; off; off >>= 1) mx = fmaxf(mx, __shfl_xor(mx, off, 64));
    float e  = (lane <= NUM_NEGS) ? expf(dj - mx) : 0.0f;
    float sn = (lane >= 1 && lane <= NUM_NEGS) ? dj : 0.0f;
    #pragma unroll
    for (int off = 32; off; off >>= 1) {
        e  += __shfl_xor(e, off, 64);
        sn += __shfl_xor(sn, off, 64);
    }
    if (lane == 0) {
        const float num   = dj;               // dots[0]
        const float lse   = mx + logf(e);
        const float chunk = lse * TDSUM - (TD0 * num + TDN * sn);
        const float v     = padraw ? 0.0f : 1.0f;
        const float sim   = 1.0f - fminf(fmaxf(num, -1.0f), 1.0f);
        partials[bq] = make_float4(chunk * v, sim * v, v, 0.0f);
    }
}

// ---------- fallback: fp32 gather (used only if ws too small) ----------
__global__ __launch_bounds__(256) void ce_main_fp32_kernel(
    const float* __restrict__ s, const float* __restrict__ c,
    const int* __restrict__ pad, const int* __restrict__ valid,
    const int* __restrict__ inds, float4* __restrict__ partials)
{
    const int p    = blockIdx.x;
    const int x    = p & 7;
    const int i    = p >> 3;
    const int b    = x + ((i >> 9) << 3);
    const int wave = threadIdx.x >> 6;
    const int lane = threadIdx.x & 63;
    const int q    = (i & 511) * 4 + wave;
    const int bq   = b * NM + q;

    int col_r = bq, row_r = bq;
    int vraw = 1;
    if (lane >= 1 && lane <= NUM_NEGS) {
        const size_t si = ((size_t)bq * NUM_NEGS + (lane - 1)) * 3;
        const int bb = inds[si + 0];
        const int rr = inds[si + 1];
        const int cc = inds[si + 2];
        col_r = bb * NM + cc;
        row_r = bb * NM + rr;
        vraw  = valid[((size_t)bb * NM + rr) * NM + cc];
    }
    const int padraw = pad[(size_t)bq * M];

    const float4* sp = reinterpret_cast<const float4*>(s + (size_t)bq * D);
    const float4 s0 = sp[2 * lane];
    const float4 s1 = sp[2 * lane + 1];

    float dotreg = 0.0f;
    #pragma unroll
    for (int j = 0; j <= NUM_NEGS; ++j) {
        const int col = __shfl(col_r, j, 64);
        const int row = __shfl(row_r, j, 64);
        const float4* cp = reinterpret_cast<const float4*>(c + (size_t)col * D);
        const float4 c0 = cp[2 * lane];
        const float4 c1 = cp[2 * lane + 1];
        float4 t0 = s0, t1 = s1;
        if (row != bq) {
            const float4* spx = reinterpret_cast<const float4*>(s + (size_t)row * D);
            t0 = spx[2 * lane];
            t1 = spx[2 * lane + 1];
        }
        float sum = c0.x * t0.x + c0.y * t0.y + c0.z * t0.z + c0.w * t0.w
                  + c1.x * t1.x + c1.y * t1.y + c1.z * t1.z + c1.w * t1.w;
        #pragma unroll
        for (int off = 32; off; off >>= 1) sum += __shfl_xor(sum, off, 64);
        if (lane == j) dotreg = sum;
    }

    float dj = (lane <= NUM_NEGS) ? dotreg : -INFINITY;
    if (lane >= 1 && lane <= NUM_NEGS && !vraw) dj = 0.0f;
    float mx = dj;
    #pragma unroll
    for (int off = 32; off; off >>= 1) mx = fmaxf(mx, __shfl_xor(mx, off, 64));
    float e  = (lane <= NUM_NEGS) ? expf(dj - mx) : 0.0f;
    float sn = (lane >= 1 && lane <= NUM_NEGS) ? dj : 0.0f;
    #pragma unroll
    for (int off = 32; off; off >>= 1) {
        e  += __shfl_xor(e, off, 64);
        sn += __shfl_xor(sn, off, 64);
    }
    if (lane == 0) {
        const float num   = dj;
        const float lse   = mx + logf(e);
        const float chunk = lse * TDSUM - (TD0 * num + TDN * sn);
        const float v     = padraw ? 0.0f : 1.0f;
        const float sim   = 1.0f - fminf(fmaxf(num, -1.0f), 1.0f);
        partials[bq] = make_float4(chunk * v, sim * v, v, 0.0f);
    }
}

// Stage 2: 64 blocks x 256 threads, grid-stride over NBQ, one partial per block.
__global__ __launch_bounds__(256) void reduce_kernel(
    const float4* __restrict__ partials, float4* __restrict__ blk)
{
    __shared__ float red[3][4];
    float a = 0.0f, bsum = 0.0f, cnt = 0.0f;
    for (int i = blockIdx.x * 256 + threadIdx.x; i < NBQ; i += 64 * 256) {
        float4 pr = partials[i];
        a += pr.x; bsum += pr.y; cnt += pr.z;
    }
    #pragma unroll
    for (int off = 32; off; off >>= 1) {
        a    += __shfl_down(a, off, 64);
        bsum += __shfl_down(bsum, off, 64);
        cnt  += __shfl_down(cnt, off, 64);
    }
    const int wave = threadIdx.x >> 6;
    const int lane = threadIdx.x & 63;
    if (lane == 0) { red[0][wave] = a; red[1][wave] = bsum; red[2][wave] = cnt; }
    __syncthreads();
    if (threadIdx.x == 0) {
        blk[blockIdx.x] = make_float4(red[0][0] + red[0][1] + red[0][2] + red[0][3],
                                      red[1][0] + red[1][1] + red[1][2] + red[1][3],
                                      red[2][0] + red[2][1] + red[2][2] + red[2][3],
                                      0.0f);
    }
}

__global__ void finalize_kernel(const float4* __restrict__ blk,
                                float* __restrict__ out) {
    const int lane = threadIdx.x & 63;
    float4 pr = blk[lane];
    float a = pr.x, bsum = pr.y, cnt = pr.z;
    #pragma unroll
    for (int off = 32; off; off >>= 1) {
        a    += __shfl_down(a, off, 64);
        bsum += __shfl_down(bsum, off, 64);
        cnt  += __shfl_down(cnt, off, 64);
    }
    if (lane == 0) {
        out[0] = a / cnt;     // ce_loss
        out[1] = bsum / cnt;  // sim_loss
    }
}

extern "C" void kernel_launch(void* const* d_in, const int* in_sizes, int n_in,
                              void* d_out, int out_size, void* d_ws, size_t ws_size,
                              hipStream_t stream) {
    const float* s_ptr   = (const float*)d_in[0];
    const float* c_ptr   = (const float*)d_in[1];
    const int*   pad_ptr = (const int*)d_in[2];
    const int*   val_ptr = (const int*)d_in[3];
    const int*   ind_ptr = (const int*)d_in[4];
    float*       out_ptr = (float*)d_out;

    // ws layout: [0, 512K) partials; [512K, +1K) blk; [1M, 1M+32M) c_bf16
    float4* partials = (float4*)d_ws;
    float4* blk      = (float4*)((char*)d_ws + (size_t)NBQ * sizeof(float4));
    uint4*  cb       = (uint4*)((char*)d_ws + (1u << 20));
    const size_t need = (1u << 20) + (size_t)B * NM * D * 2;

    if (ws_size >= need) {
        convert_c_kernel<<<8192, 256, 0, stream>>>(c_ptr, cb);
        ce_main_bf16_kernel<<<NBQ / 4, 256, 0, stream>>>(s_ptr, cb, pad_ptr,
                                                         val_ptr, ind_ptr, partials);
    } else {
        ce_main_fp32_kernel<<<NBQ / 4, 256, 0, stream>>>(s_ptr, c_ptr, pad_ptr,
                                                         val_ptr, ind_ptr, partials);
    }
    reduce_kernel<<<64, 256, 0, stream>>>(partials, blk);
    finalize_kernel<<<1, 64, 0, stream>>>(blk, out_ptr);
}

// Round 9
// 122.966 us; speedup vs baseline: 1.2085x; 1.2085x over previous
//
#include <hip/hip_runtime.h>
#include <math.h>

#define B 16
#define N 32
#define M 64
#define D 512
#define NM (N * M)          // 2048
#define NBQ (B * NM)        // 32768
#define NUM_NEGS 32
#define SMOOTHING 0.1f
#define TD0 (1.0f - SMOOTHING)                    // 0.9
#define TDN (SMOOTHING / (float)(NUM_NEGS - 1))   // 0.1/31
#define TDSUM (TD0 + (float)NUM_NEGS * TDN)

// Matches the return type of __builtin_amdgcn_cvt_pkrtz and the V2h params
// of __builtin_amdgcn_fdot2 on gfx950 (clang uses __fp16 for 'h').
typedef __fp16 half2v __attribute__((ext_vector_type(2)));

// pack two f32 -> f16x2 (v_cvt_pkrtz_f16_f32)
__device__ __forceinline__ unsigned int pkh(float lo, float hi) {
    half2v h = __builtin_amdgcn_cvt_pkrtz(lo, hi);
    return __builtin_bit_cast(unsigned int, h);
}

__device__ __forceinline__ float fdot2_acc(unsigned int a, unsigned int b, float acc) {
#if __has_builtin(__builtin_amdgcn_fdot2)
    return __builtin_amdgcn_fdot2(__builtin_bit_cast(half2v, a),
                                  __builtin_bit_cast(half2v, b), acc, false);
#else
    half2v ha = __builtin_bit_cast(half2v, a);
    half2v hb = __builtin_bit_cast(half2v, b);
    return acc + (float)ha.x * (float)hb.x + (float)ha.y * (float)hb.y;
#endif
}

__device__ __forceinline__ float dot8h(uint4 a, uint4 b) {
    float acc = fdot2_acc(a.x, b.x, 0.0f);
    acc = fdot2_acc(a.y, b.y, acc);
    acc = fdot2_acc(a.z, b.z, acc);
    acc = fdot2_acc(a.w, b.w, acc);
    return acc;
}

__device__ __forceinline__ uint4 load_s16(const float* __restrict__ s, int row, int lane) {
    const float4* sp = reinterpret_cast<const float4*>(s + (size_t)row * D);
    const float4 a0 = sp[2 * lane];
    const float4 a1 = sp[2 * lane + 1];
    uint4 r;
    r.x = pkh(a0.x, a0.y); r.y = pkh(a0.z, a0.w);
    r.z = pkh(a1.x, a1.y); r.w = pkh(a1.z, a1.w);
    return r;
}

// Streaming c -> f16 (16,777,216 floats, 8 per thread, 8192 x 256 exact).
__global__ __launch_bounds__(256) void convert_c_kernel(
    const float* __restrict__ c, uint4* __restrict__ cb)
{
    const size_t i = (size_t)blockIdx.x * 256 + threadIdx.x;
    const float4* cp = reinterpret_cast<const float4*>(c);
    const float4 a = cp[2 * i];
    const float4 b4 = cp[2 * i + 1];
    uint4 w;
    w.x = pkh(a.x, a.y);   w.y = pkh(a.z, a.w);
    w.z = pkh(b4.x, b4.y); w.w = pkh(b4.z, b4.w);
    cb[i] = w;
}

// ---------- main kernel: block-per-q, 4 waves, f16 dots ----------
__global__ __launch_bounds__(256) void ce_main_f16_kernel(
    const float* __restrict__ s,              // (B, NM, D) fp32
    const uint4* __restrict__ cb,             // (B*NM, D/8) f16-packed rows
    const int* __restrict__ pad,
    const int* __restrict__ valid,
    const int* __restrict__ inds,
    float4* __restrict__ partials)
{
    __shared__ float dots[NUM_NEGS + 1];
    __shared__ int   colsh[NUM_NEGS + 1];
    __shared__ int   rowsh[NUM_NEGS + 1];
    __shared__ unsigned char vmsk[NUM_NEGS + 1];

    // XCD-batch affinity swizzle: XCD x owns batches {x, x+8}.
    const int p  = blockIdx.x;
    const int x  = p & 7;
    const int i  = p >> 3;
    const int b  = x + ((i >> 11) << 3);
    const int q  = i & (NM - 1);
    const int bq = b * NM + q;

    const int tid  = threadIdx.x;
    const int wave = tid >> 6;
    const int lane = tid & 63;

    // Compact setup phase: indices + valid gather by 33 threads.
    if (tid < NUM_NEGS + 1) {
        int col, srow, vb;
        if (tid == 0) {
            col = bq; srow = bq; vb = 1;
        } else {
            size_t si = ((size_t)bq * NUM_NEGS + (tid - 1)) * 3;
            int bb = inds[si + 0];
            int rr = inds[si + 1];
            int cc = inds[si + 2];
            col  = bb * NM + cc;
            srow = bb * NM + rr;
            vb   = valid[((size_t)bb * NM + rr) * NM + cc] ? 1 : 0;
        }
        colsh[tid] = col;
        rowsh[tid] = srow;
        vmsk[tid]  = (unsigned char)vb;
    }
    __syncthreads();

    // Own s-row fragment (elems 8*lane..8*lane+7) -> f16 registers, once per q.
    const uint4 sh = load_s16(s, bq, lane);

    // 2 groups of 4 concurrent dots: wave w handles {w, w+4, ..., w+28}.
    #pragma unroll
    for (int g = 0; g < 2; ++g) {
        const int j0 = wave + g * 16;
        const int j1 = j0 + 4, j2 = j0 + 8, j3 = j0 + 12;
        const uint4 w0 = cb[(size_t)colsh[j0] * (D / 8) + lane];
        const uint4 w1 = cb[(size_t)colsh[j1] * (D / 8) + lane];
        const uint4 w2 = cb[(size_t)colsh[j2] * (D / 8) + lane];
        const uint4 w3 = cb[(size_t)colsh[j3] * (D / 8) + lane];
        uint4 t0 = sh, t1 = sh, t2 = sh, t3 = sh;
        if (rowsh[j0] != bq) t0 = load_s16(s, rowsh[j0], lane);  // wave-uniform,
        if (rowsh[j1] != bq) t1 = load_s16(s, rowsh[j1], lane);  // never taken for
        if (rowsh[j2] != bq) t2 = load_s16(s, rowsh[j2], lane);  // these inputs
        if (rowsh[j3] != bq) t3 = load_s16(s, rowsh[j3], lane);
        float u0 = dot8h(w0, t0);
        float u1 = dot8h(w1, t1);
        float u2 = dot8h(w2, t2);
        float u3 = dot8h(w3, t3);
        #pragma unroll
        for (int off = 32; off; off >>= 1) {
            u0 += __shfl_xor(u0, off, 64);
            u1 += __shfl_xor(u1, off, 64);
            u2 += __shfl_xor(u2, off, 64);
            u3 += __shfl_xor(u3, off, 64);
        }
        if (lane == 0) {
            dots[j0] = vmsk[j0] ? u0 : 0.0f;
            dots[j1] = vmsk[j1] ? u1 : 0.0f;
            dots[j2] = vmsk[j2] ? u2 : 0.0f;
            dots[j3] = vmsk[j3] ? u3 : 0.0f;
        }
    }
    if (wave == 0) {   // dot 32
        const uint4 w0 = cb[(size_t)colsh[32] * (D / 8) + lane];
        uint4 t0 = sh;
        if (rowsh[32] != bq) t0 = load_s16(s, rowsh[32], lane);
        float u = dot8h(w0, t0);
        #pragma unroll
        for (int off = 32; off; off >>= 1) u += __shfl_xor(u, off, 64);
        if (lane == 0) dots[32] = vmsk[32] ? u : 0.0f;
    }
    __syncthreads();

    // Wave-parallel epilogue on wave 0.
    if (wave == 0) {
        const float dj = (lane <= NUM_NEGS) ? dots[lane] : -INFINITY;
        float mx = dj;
        #pragma unroll
        for (int off = 32; off; off >>= 1) mx = fmaxf(mx, __shfl_xor(mx, off, 64));
        float e  = (lane <= NUM_NEGS) ? expf(dj - mx) : 0.0f;
        float sn = (lane >= 1 && lane <= NUM_NEGS) ? dj : 0.0f;
        #pragma unroll
        for (int off = 32; off; off >>= 1) {
            e  += __shfl_xor(e, off, 64);
            sn += __shfl_xor(sn, off, 64);
        }
        if (lane == 0) {
            const float num   = dj;             // dots[0]
            const float lse   = mx + logf(e);
            const float chunk = lse * TDSUM - (TD0 * num + TDN * sn);
            const float v     = pad[(size_t)bq * M] ? 0.0f : 1.0f;
            const float sim   = 1.0f - fminf(fmaxf(num, -1.0f), 1.0f);
            partials[bq] = make_float4(chunk * v, sim * v, v, 0.0f);
        }
    }
}

// ---------- fallback: fp32 gather, same skeleton (used only if ws too small) ----------
__global__ __launch_bounds__(256) void ce_main_fp32_kernel(
    const float* __restrict__ s, const float* __restrict__ c,
    const int* __restrict__ pad, const int* __restrict__ valid,
    const int* __restrict__ inds, float4* __restrict__ partials)
{
    __shared__ float dots[NUM_NEGS + 1];
    __shared__ int   colsh[NUM_NEGS + 1];
    __shared__ int   rowsh[NUM_NEGS + 1];
    __shared__ unsigned char vmsk[NUM_NEGS + 1];

    const int p  = blockIdx.x;
    const int x  = p & 7;
    const int i  = p >> 3;
    const int b  = x + ((i >> 11) << 3);
    const int q  = i & (NM - 1);
    const int bq = b * NM + q;

    const int tid  = threadIdx.x;
    const int wave = tid >> 6;
    const int lane = tid & 63;

    if (tid < NUM_NEGS + 1) {
        int col, srow, vb;
        if (tid == 0) { col = bq; srow = bq; vb = 1; }
        else {
            size_t si = ((size_t)bq * NUM_NEGS + (tid - 1)) * 3;
            int bb = inds[si + 0]; int rr = inds[si + 1]; int cc = inds[si + 2];
            col = bb * NM + cc; srow = bb * NM + rr;
            vb  = valid[((size_t)bb * NM + rr) * NM + cc] ? 1 : 0;
        }
        colsh[tid] = col; rowsh[tid] = srow; vmsk[tid] = (unsigned char)vb;
    }
    __syncthreads();

    const float4* sp = reinterpret_cast<const float4*>(s + (size_t)bq * D);
    const float4 s0 = sp[lane];
    const float4 s1 = sp[lane + 64];

    for (int j = wave; j < NUM_NEGS + 1; j += 4) {
        const float4* cp = reinterpret_cast<const float4*>(c + (size_t)colsh[j] * D);
        float4 c0 = cp[lane];
        float4 c1 = cp[lane + 64];
        float4 t0 = s0, t1 = s1;
        if (rowsh[j] != bq) {
            const float4* spx = reinterpret_cast<const float4*>(s + (size_t)rowsh[j] * D);
            t0 = spx[lane]; t1 = spx[lane + 64];
        }
        float sum = c0.x * t0.x + c0.y * t0.y + c0.z * t0.z + c0.w * t0.w
                  + c1.x * t1.x + c1.y * t1.y + c1.z * t1.z + c1.w * t1.w;
        #pragma unroll
        for (int off = 32; off; off >>= 1) sum += __shfl_down(sum, off, 64);
        if (lane == 0) dots[j] = vmsk[j] ? sum : 0.0f;
    }
    __syncthreads();

    if (wave == 0) {
        const float dj = (lane <= NUM_NEGS) ? dots[lane] : -INFINITY;
        float mx = dj;
        #pragma unroll
        for (int off = 32; off; off >>= 1) mx = fmaxf(mx, __shfl_xor(mx, off, 64));
        float e  = (lane <= NUM_NEGS) ? expf(dj - mx) : 0.0f;
        float sn = (lane >= 1 && lane <= NUM_NEGS) ? dj : 0.0f;
        #pragma unroll
        for (int off = 32; off; off >>= 1) { e += __shfl_xor(e, off, 64); sn += __shfl_xor(sn, off, 64); }
        if (lane == 0) {
            const float num   = dj;
            const float lse   = mx + logf(e);
            const float chunk = lse * TDSUM - (TD0 * num + TDN * sn);
            const float v     = pad[(size_t)bq * M] ? 0.0f : 1.0f;
            const float sim   = 1.0f - fminf(fmaxf(num, -1.0f), 1.0f);
            partials[bq] = make_float4(chunk * v, sim * v, v, 0.0f);
        }
    }
}

// Stage 2: 64 blocks x 256 threads, grid-stride over NBQ, one partial per block.
__global__ __launch_bounds__(256) void reduce_kernel(
    const float4* __restrict__ partials, float4* __restrict__ blk)
{
    __shared__ float red[3][4];
    float a = 0.0f, bsum = 0.0f, cnt = 0.0f;
    for (int i = blockIdx.x * 256 + threadIdx.x; i < NBQ; i += 64 * 256) {
        float4 pr = partials[i];
        a += pr.x; bsum += pr.y; cnt += pr.z;
    }
    #pragma unroll
    for (int off = 32; off; off >>= 1) {
        a    += __shfl_down(a, off, 64);
        bsum += __shfl_down(bsum, off, 64);
        cnt  += __shfl_down(cnt, off, 64);
    }
    const int wave = threadIdx.x >> 6;
    const int lane = threadIdx.x & 63;
    if (lane == 0) { red[0][wave] = a; red[1][wave] = bsum; red[2][wave] = cnt; }
    __syncthreads();
    if (threadIdx.x == 0) {
        blk[blockIdx.x] = make_float4(red[0][0] + red[0][1] + red[0][2] + red[0][3],
                                      red[1][0] + red[1][1] + red[1][2] + red[1][3],
                                      red[2][0] + red[2][1] + red[2][2] + red[2][3],
                                      0.0f);
    }
}

__global__ void finalize_kernel(const float4* __restrict__ blk,
                                float* __restrict__ out) {
    const int lane = threadIdx.x & 63;
    float4 pr = blk[lane];
    float a = pr.x, bsum = pr.y, cnt = pr.z;
    #pragma unroll
    for (int off = 32; off; off >>= 1) {
        a    += __shfl_down(a, off, 64);
        bsum += __shfl_down(bsum, off, 64);
        cnt  += __shfl_down(cnt, off, 64);
    }
    if (lane == 0) {
        out[0] = a / cnt;     // ce_loss
        out[1] = bsum / cnt;  // sim_loss
    }
}

extern "C" void kernel_launch(void* const* d_in, const int* in_sizes, int n_in,
                              void* d_out, int out_size, void* d_ws, size_t ws_size,
                              hipStream_t stream) {
    const float* s_ptr   = (const float*)d_in[0];
    const float* c_ptr   = (const float*)d_in[1];
    const int*   pad_ptr = (const int*)d_in[2];
    const int*   val_ptr = (const int*)d_in[3];
    const int*   ind_ptr = (const int*)d_in[4];
    float*       out_ptr = (float*)d_out;

    // ws layout: [0, 512K) partials; [512K, +1K) blk; [1M, 1M+32M) c_f16
    float4* partials = (float4*)d_ws;
    float4* blk      = (float4*)((char*)d_ws + (size_t)NBQ * sizeof(float4));
    uint4*  cb       = (uint4*)((char*)d_ws + (1u << 20));
    const size_t need = (1u << 20) + (size_t)B * NM * D * 2;

    if (ws_size >= need) {
        convert_c_kernel<<<8192, 256, 0, stream>>>(c_ptr, cb);
        ce_main_f16_kernel<<<NBQ, 256, 0, stream>>>(s_ptr, cb, pad_ptr, val_ptr,
                                                    ind_ptr, partials);
    } else {
        ce_main_fp32_kernel<<<NBQ, 256, 0, stream>>>(s_ptr, c_ptr, pad_ptr, val_ptr,
                                                     ind_ptr, partials);
    }
    reduce_kernel<<<64, 256, 0, stream>>>(partials, blk);
    finalize_kernel<<<1, 64, 0, stream>>>(blk, out_ptr);
}